// Round 10
// baseline (241.217 us; speedup 1.0000x reference)
//
#include <hip/hip_runtime.h>
#include <hip/hip_bf16.h>
#include <math.h>

// Problem constants (B,T,M,C,H = 4,2048,256,512,8; D=64)
#define B_ 4
#define T_ 2048
#define M_ 256
#define C_ 512
#define H_ 8
#define D_ 64
#define TC3 1536
// 1/sqrt(64) * log2(e): folded into Q so all softmax exps are native exp2
#define QSCALE2 0.18033688f

typedef _Float16 half_t;
typedef _Float16 half8 __attribute__((ext_vector_type(8)));
typedef _Float16 half4 __attribute__((ext_vector_type(4)));
typedef float floatx4 __attribute__((ext_vector_type(4)));

// ---- async global->LDS, 16B per lane; lane i lands at ldsbase + i*16B.
// One 64-lane call stages 1024 B = 8 rows of a 64-half (128 B) tile.
__device__ __forceinline__ void gload_lds16(const half_t* g, half_t* lds) {
  __builtin_amdgcn_global_load_lds(
      (const __attribute__((address_space(1))) unsigned int*)g,
      (__attribute__((address_space(3))) unsigned int*)(unsigned)(unsigned long long)(void*)lds,
      16, 0, 0);
}

__device__ __forceinline__ floatx4 mfma16(half8 a, half8 b, floatx4 c) {
  return __builtin_amdgcn_mfma_f32_16x16x32_f16(a, b, c, 0, 0, 0);
}
__device__ __forceinline__ floatx4 mfma16k16(half4 a, half4 b, floatx4 c) {
  return __builtin_amdgcn_mfma_f32_16x16x16f16(a, b, c, 0, 0, 0);
}

// Swizzled LDS tiles: 64-half rows, 8 chunks of 8 halves; slot = chunk ^ (row&7)
__device__ __forceinline__ half8 frag64(const half_t* lds, int row, int kc, int quad) {
  int slot = ((kc << 2) + quad) ^ (row & 7);
  return *(const half8*)(lds + row * 64 + slot * 8);
}

// ---------------------------------------------------------------------------
// Fused conversions: blocks [0,2304) transpose 5 weight mats fp32->fp16
// k-major; blocks [2304,3456) convert x,y fp32->fp16.
// ---------------------------------------------------------------------------
__global__ __launch_bounds__(256) void conv_all(
    const float* x, half_t* xo, const float* y, half_t* yo,
    const float* w0, const float* w1, const float* w2, const float* w3, const float* w4,
    half_t* o0, half_t* o1, half_t* o2, half_t* o3, half_t* o4) {
  __shared__ float tile[32][33];
  const int tid = threadIdx.x;
  if (blockIdx.x < 2304) {
    int blk = blockIdx.x;
    const float* src; half_t* dst; int N;
    if (blk < 768)       { src = w0; dst = o0; N = 1536; }
    else if (blk < 1536) { src = w1; dst = o1; N = 1536; blk -= 768; }
    else if (blk < 1792) { src = w2; dst = o2; N = 512;  blk -= 1536; }
    else if (blk < 2048) { src = w3; dst = o3; N = 512;  blk -= 1792; }
    else                 { src = w4; dst = o4; N = 512;  blk -= 2048; }
    const int ntx = N >> 5;
    const int tk = blk / ntx, tn = blk % ntx;
    const int r = tid >> 3, c = (tid & 7) * 4;
    float4 v = *(const float4*)(src + (size_t)(tk * 32 + r) * N + tn * 32 + c);
    tile[r][c] = v.x; tile[r][c + 1] = v.y; tile[r][c + 2] = v.z; tile[r][c + 3] = v.w;
    __syncthreads();
    half4 h;
#pragma unroll
    for (int j = 0; j < 4; ++j) h[j] = (half_t)tile[c + j][r];
    *(half4*)(dst + (size_t)(tn * 32 + r) * 512 + tk * 32 + c) = h;
  } else {
    const int nx = B_ * T_ * C_, ny = B_ * M_ * C_;
    const int n4x = nx >> 2, tot = n4x + (ny >> 2);
    int i = (blockIdx.x - 2304) * 256 + tid;
    const int stride = (gridDim.x - 2304) * 256;
    for (; i < tot; i += stride) {
      const float4* s; half_t* d; int idx;
      if (i < n4x) { s = (const float4*)x; d = xo; idx = i; }
      else { s = (const float4*)y; d = yo; idx = i - n4x; }
      float4 v = s[idx];
      half4 h; h[0] = (half_t)v.x; h[1] = (half_t)v.y; h[2] = (half_t)v.z; h[3] = (half_t)v.w;
      *(half4*)(d + idx * 4) = h;
    }
  }
}

// ---------------------------------------------------------------------------
// GEMM core: 128x128, K=512, BK=64.
// ---------------------------------------------------------------------------
struct GemmAcc { floatx4 a[4][4]; };

__device__ __forceinline__ void gemm_core64(
    const half_t* __restrict__ A, const half_t* __restrict__ Wt,
    int rowBase, int colBase, GemmAcc& g,
    half_t* As, half_t* Bs, int tid) {
  const int lane = tid & 63, wave = tid >> 6;
  const int wm = wave >> 1, wn = wave & 1;
  const int qd = lane >> 4, lr = lane & 15;
  const int rr = lane >> 3, cc = lane & 7;
  const int cs = cc ^ rr;
#pragma unroll
  for (int mi = 0; mi < 4; ++mi)
#pragma unroll
    for (int ni = 0; ni < 4; ++ni)
#pragma unroll
      for (int r = 0; r < 4; ++r) g.a[mi][ni][r] = 0.f;
  for (int k0 = 0; k0 < 512; k0 += 64) {
    __syncthreads();
#pragma unroll
    for (int j = 0; j < 4; ++j) {
      int row = wave * 32 + j * 8 + rr;
      gload_lds16(A + (size_t)(rowBase + row) * 512 + k0 + cs * 8, As + (wave * 32 + j * 8) * 64);
      gload_lds16(Wt + (size_t)(colBase + row) * 512 + k0 + cs * 8, Bs + (wave * 32 + j * 8) * 64);
    }
    __syncthreads();
#pragma unroll
    for (int kc = 0; kc < 2; ++kc) {
      half8 af[4], bf[4];
#pragma unroll
      for (int mi = 0; mi < 4; ++mi) af[mi] = frag64(As, wm * 64 + mi * 16 + lr, kc, qd);
#pragma unroll
      for (int ni = 0; ni < 4; ++ni) bf[ni] = frag64(Bs, wn * 64 + ni * 16 + lr, kc, qd);
#pragma unroll
      for (int mi = 0; mi < 4; ++mi)
#pragma unroll
        for (int ni = 0; ni < 4; ++ni)
          g.a[mi][ni] = mfma16(af[mi], bf[ni], g.a[mi][ni]);
    }
  }
}

// ---------------------------------------------------------------------------
// Fused QK + V^T projections. Blocks [0,576): QK for x,y (Q cols pre-scaled
// by QSCALE2 = 0.125*log2e). Blocks [576,864): vT = Wv^T @ x^T (+row bias).
// ---------------------------------------------------------------------------
__global__ __launch_bounds__(256) void gemm_qkvt(
    const half_t* __restrict__ x16, const half_t* __restrict__ y16,
    const half_t* __restrict__ WxT, const half_t* __restrict__ WyT,
    const float* __restrict__ bqx, const float* __restrict__ bqy,
    half_t* __restrict__ qkvx, half_t* __restrict__ qkvy,
    half_t* __restrict__ vTx, half_t* __restrict__ vTy) {
  __shared__ __align__(16) half_t As[128 * 64];
  __shared__ __align__(16) half_t Bs[128 * 64];
  const int tid = threadIdx.x, lane = tid & 63, wave = tid >> 6;
  const int wm = wave >> 1, wn = wave & 1;
  const int qd = lane >> 4, lr = lane & 15;
  const int bxi = blockIdx.x;
  const half_t* A; const half_t* Wt; const float* bias; half_t* out;
  int rowBase, colBase, N; bool vt;
  if (bxi < 576) {
    vt = false; N = 1024;
    colBase = (bxi & 7) * 128;
    int ry = bxi >> 3;
    if (ry < 64) { A = x16; Wt = WxT; bias = bqx; out = qkvx; rowBase = ry * 128; }
    else { A = y16; Wt = WyT; bias = bqy; out = qkvy; rowBase = (ry - 64) * 128; }
  } else {
    vt = true;
    int i = bxi - 576;
    int xx = i % 18; int rest = i / 18;
    int yy = rest & 3, zz = rest >> 2;
    rowBase = yy * 128;
    if (xx < 16) {
      A = WxT + (size_t)1024 * 512; Wt = x16 + (size_t)zz * T_ * C_; bias = bqx + 1024;
      out = vTx + (size_t)zz * C_ * T_; N = T_; colBase = xx * 128;
    } else {
      A = WyT + (size_t)1024 * 512; Wt = y16 + (size_t)zz * M_ * C_; bias = bqy + 1024;
      out = vTy + (size_t)zz * C_ * M_; N = M_; colBase = (xx - 16) * 128;
    }
  }
  GemmAcc g;
  gemm_core64(A, Wt, rowBase, colBase, g, As, Bs, tid);
  if (!vt) {
#pragma unroll
    for (int ni = 0; ni < 4; ++ni) {
      int col = colBase + wn * 64 + ni * 16 + lr;
      float csc = (col < 512) ? QSCALE2 : 1.f;
      float bc = bias[col];
#pragma unroll
      for (int mi = 0; mi < 4; ++mi) {
        int row0 = rowBase + wm * 64 + mi * 16 + qd * 4;
#pragma unroll
        for (int r = 0; r < 4; ++r)
          out[(size_t)(row0 + r) * 1024 + col] = (half_t)((g.a[mi][ni][r] + bc) * csc);
      }
    }
  } else {
#pragma unroll
    for (int ni = 0; ni < 4; ++ni) {
      int col = colBase + wn * 64 + ni * 16 + lr;
#pragma unroll
      for (int mi = 0; mi < 4; ++mi) {
        int row0 = rowBase + wm * 64 + mi * 16 + qd * 4;
#pragma unroll
        for (int r = 0; r < 4; ++r)
          out[(size_t)(row0 + r) * N + col] = (half_t)(g.a[mi][ni][r] + bias[row0 + r]);
      }
    }
  }
}

// ---------------------------------------------------------------------------
// Dual-group attention tile (log2-domain softmax): groups A/B share K/V
// fragment reads; row-sum l via ones-column MFMA.
// ---------------------------------------------------------------------------
template <bool USE_BIAS, bool DO_A, bool DIAG_A, bool DIAG_B>
__device__ __forceinline__ void attn_tile_dual(
    const half_t* __restrict__ Ks, const half_t* __restrict__ Vts,
    const float* __restrict__ Bsh, const half8* qfA, const half8* qfB,
    floatx4* oA, floatx4& lacA, floatx4* oB, floatx4& lacB,
    int qd, int lr, int thresh) {
  floatx4 sA[4], sB[4];
#pragma unroll
  for (int ks = 0; ks < 4; ++ks)
#pragma unroll
    for (int r = 0; r < 4; ++r) { sA[ks][r] = 0.f; sB[ks][r] = 0.f; }
#pragma unroll
  for (int kc = 0; kc < 2; ++kc) {
#pragma unroll
    for (int ks = 0; ks < 4; ++ks) {
      half8 kfr = frag64(Ks, ks * 16 + lr, kc, qd);
      if (DO_A) sA[ks] = mfma16(kfr, qfA[kc], sA[ks]);
      sB[ks] = mfma16(kfr, qfB[kc], sB[ks]);
    }
  }
  half4 pA[4], pB[4];
#pragma unroll
  for (int ks = 0; ks < 4; ++ks) {
    floatx4 bf;
    if (USE_BIAS) bf = *(const floatx4*)(Bsh + ks * 16 + qd * 4);
#pragma unroll
    for (int r = 0; r < 4; ++r) {
      int keyl = ks * 16 + qd * 4 + r;
      if (DO_A) {
        float t = USE_BIAS ? (sA[ks][r] + bf[r]) : sA[ks][r];
        float p1 = exp2f(t);
        if (DIAG_A && keyl > thresh) p1 = 0.f;
        pA[ks][r] = (half_t)p1;
      }
      float t2 = USE_BIAS ? (sB[ks][r] + bf[r]) : sB[ks][r];
      float p2 = exp2f(t2);
      if (DIAG_B && keyl > thresh) p2 = 0.f;
      pB[ks][r] = (half_t)p2;
    }
  }
  const half4 ones4 = {(half_t)1.f, (half_t)1.f, (half_t)1.f, (half_t)1.f};
#pragma unroll
  for (int ks = 0; ks < 4; ++ks) {
    int slot = (ks * 2 + (qd >> 1)) ^ (lr & 7);
    const half_t* vbase = Vts + slot * 8 + (qd & 1) * 4;
#pragma unroll
    for (int dt = 0; dt < 4; ++dt) {
      half4 vf = *(const half4*)(vbase + (dt * 16 + lr) * 64);
      if (DO_A) oA[dt] = mfma16k16(pA[ks], vf, oA[dt]);
      oB[dt] = mfma16k16(pB[ks], vf, oB[dt]);
    }
    if (DO_A) lacA = mfma16k16(pA[ks], ones4, lacA);
    lacB = mfma16k16(pB[ks], ones4, lacB);
  }
}

// runtime flag dispatch for one 64-key tile of the causal loop
__device__ __forceinline__ void attn_step(
    int kt, int p, int ktEnd,
    const half_t* Ks, const half_t* Vts, const float* Bsh,
    const half8* qfA, const half8* qfB,
    floatx4* oA, floatx4& lacA, floatx4* oB, floatx4& lacB,
    int qd, int lr, int thresh) {
  if (kt < p)
    attn_tile_dual<true, true, false, false>(Ks, Vts, Bsh, qfA, qfB, oA, lacA, oB, lacB, qd, lr, thresh);
  else if (kt == p)
    attn_tile_dual<true, true, true, false>(Ks, Vts, Bsh, qfA, qfB, oA, lacA, oB, lacB, qd, lr, thresh);
  else if (kt < ktEnd)
    attn_tile_dual<true, false, false, false>(Ks, Vts, Bsh, qfA, qfB, oA, lacA, oB, lacB, qd, lr, thresh);
  else
    attn_tile_dual<true, false, false, true>(Ks, Vts, Bsh, qfA, qfB, oA, lacA, oB, lacB, qd, lr, thresh);
}

__device__ __forceinline__ void attn_store2(
    half_t* __restrict__ dst, const floatx4* o, floatx4 lac,
    int b, int qbase, int h, int qd, int lr) {
  floatx4 inv;
#pragma unroll
  for (int r = 0; r < 4; ++r) inv[r] = 1.f / lac[r];
#pragma unroll
  for (int dt = 0; dt < 4; ++dt)
#pragma unroll
    for (int r = 0; r < 4; ++r)
      dst[(size_t)(b * T_ + qbase + qd * 4 + r) * C_ + h * D_ + dt * 16 + lr] =
          (half_t)(o[dt][r] * inv[r]);
}

// ---------------------------------------------------------------------------
// Balanced causal self-attention (r4 structure + exp2 domain): block = (bh,p)
// pair (p, 31-p); wave = 16q-low (A) + 16q-high (B); 1 k-tile per barrier.
// 33 KB LDS -> 4 blocks/CU.
// ---------------------------------------------------------------------------
__global__ __launch_bounds__(256) void self_attn_reg(
    const half_t* __restrict__ qkv, const half_t* __restrict__ vT,
    const float* __restrict__ biasb, half_t* __restrict__ sval) {
  __shared__ __align__(16) half_t Qs[128 * 64];
  __shared__ __align__(16) half_t Ks[64 * 64];
  __shared__ __align__(16) half_t Vts[64 * 64];
  __shared__ __align__(16) float Bsh[64];
  const int tid = threadIdx.x, lane = tid & 63, wave = tid >> 6;
  const int p = blockIdx.x & 15;
  const int bh = blockIdx.x >> 4;
  const int b = bh >> 3, h = bh & 7;
  const int qbL = p * 64, qbH = (31 - p) * 64;
  const int qd = lane >> 4, lr = lane & 15;
  const int rr = lane >> 3, cc = lane & 7;
  const int cs = cc ^ rr;

  // stage Q: rows 0..63 = low tile, 64..127 = high tile
#pragma unroll
  for (int j = 0; j < 4; ++j) {
    int rowIdx = wave * 32 + j * 8 + rr;
    int grow = (rowIdx < 64) ? (qbL + rowIdx) : (qbH + rowIdx - 64);
    gload_lds16(qkv + (size_t)(b * T_ + grow) * 1024 + h * D_ + cs * 8,
                Qs + (wave * 32 + j * 8) * 64);
  }
  __syncthreads();
  half8 qfA[2], qfB[2];
#pragma unroll
  for (int kc = 0; kc < 2; ++kc) {
    qfA[kc] = frag64(Qs, wave * 16 + lr, kc, qd);
    qfB[kc] = frag64(Qs, 64 + wave * 16 + lr, kc, qd);
  }
  floatx4 oA[4], oB[4], lacA, lacB;
#pragma unroll
  for (int dt = 0; dt < 4; ++dt)
#pragma unroll
    for (int r = 0; r < 4; ++r) { oA[dt][r] = 0.f; oB[dt][r] = 0.f; }
#pragma unroll
  for (int r = 0; r < 4; ++r) { lacA[r] = 0.f; lacB[r] = 0.f; }
  const int thresh = wave * 16 + lr;
  const int ktEnd = 31 - p;

  for (int kt = 0; kt <= ktEnd; ++kt) {
    const int kb = kt * 64;
    __syncthreads();
#pragma unroll
    for (int j = 0; j < 2; ++j) {
      int row = wave * 16 + j * 8 + rr;
      gload_lds16(qkv + (size_t)(b * T_ + kb + row) * 1024 + C_ + h * D_ + cs * 8,
                  Ks + (wave * 16 + j * 8) * 64);
      gload_lds16(vT + ((size_t)bh * 64 + row) * T_ + kb + cs * 8,
                  Vts + (wave * 16 + j * 8) * 64);
    }
    if (tid < 64) Bsh[tid] = biasb[bh * T_ + kb + tid];
    __syncthreads();
    attn_step(kt, p, ktEnd, Ks, Vts, Bsh, qfA, qfB, oA, lacA, oB, lacB, qd, lr, thresh);
  }
  attn_store2(sval, oA, lacA, b, qbL + wave * 16, h, qd, lr);
  attn_store2(sval, oB, lacB, b, qbH + wave * 16, h, qd, lr);
}

// ---------------------------------------------------------------------------
// Fused bias + cross-attention, 32 KB LDS (5 blocks/CU).
// Blocks [0,512): per-key bias (log2 domain), Qy staged in 2 chunks of 128.
// Blocks [512,1024): cross-attn x->y, 1 k-tile/barrier.
// ---------------------------------------------------------------------------
__global__ __launch_bounds__(256) void bias_cross(
    const half_t* __restrict__ qkvx, const half_t* __restrict__ qkvy,
    const half_t* __restrict__ vTy, float* __restrict__ biasb,
    half_t* __restrict__ cval) {
  __shared__ __align__(16) half_t smem[16384];   // 32 KB
  const int tid = threadIdx.x, lane = tid & 63, wave = tid >> 6;
  const int qd = lane >> 4, lr = lane & 15;
  const int rr = lane >> 3, cc = lane & 7;
  const int cs = cc ^ rr;
  if (blockIdx.x < 512) {
    half_t* Qy = smem;            // 128x64 chunk
    half_t* Kx = smem + 8192;     // 128x64
    const int bh = blockIdx.x >> 4;
    const int tb = (blockIdx.x & 15) * 128;
    const int b = bh >> 3, h = bh & 7;
    // stage Kx + Qy chunk 0
#pragma unroll
    for (int j = 0; j < 4; ++j) {
      int r = wave * 32 + j * 8 + rr;
      gload_lds16(qkvx + (size_t)(b * T_ + tb + r) * 1024 + C_ + h * D_ + cs * 8,
                  Kx + (wave * 32 + j * 8) * 64);
      gload_lds16(qkvy + (size_t)(b * M_ + r) * 1024 + h * D_ + cs * 8,
                  Qy + (wave * 32 + j * 8) * 64);
    }
    __syncthreads();
    half8 kf[2][2];
#pragma unroll
    for (int nt = 0; nt < 2; ++nt)
#pragma unroll
      for (int kc = 0; kc < 2; ++kc)
        kf[nt][kc] = frag64(Kx, wave * 32 + nt * 16 + lr, kc, qd);
    float ls[2] = {0.f, 0.f}, wsp[2] = {0.f, 0.f};
    for (int chunk = 0; chunk < 2; ++chunk) {
      if (chunk) {
        __syncthreads();   // all waves done reading chunk 0
#pragma unroll
        for (int j = 0; j < 4; ++j) {
          int r = wave * 32 + j * 8 + rr;
          gload_lds16(qkvy + (size_t)(b * M_ + 128 + r) * 1024 + h * D_ + cs * 8,
                      Qy + (wave * 32 + j * 8) * 64);
        }
        __syncthreads();
      }
      for (int mt = 0; mt < 8; ++mt) {
        half8 af[2];
#pragma unroll
        for (int kc = 0; kc < 2; ++kc) af[kc] = frag64(Qy, mt * 16 + lr, kc, qd);
#pragma unroll
        for (int nt = 0; nt < 2; ++nt) {
          floatx4 s;
#pragma unroll
          for (int r = 0; r < 4; ++r) s[r] = 0.f;
#pragma unroll
          for (int kc = 0; kc < 2; ++kc) s = mfma16(af[kc], kf[nt][kc], s);
#pragma unroll
          for (int r = 0; r < 4; ++r) {
            float e = exp2f(s[r]);
            ls[nt] += e;
            wsp[nt] += e * s[r];
          }
        }
      }
    }
#pragma unroll
    for (int nt = 0; nt < 2; ++nt) {
      ls[nt] += __shfl_xor(ls[nt], 16, 64);
      ls[nt] += __shfl_xor(ls[nt], 32, 64);
      wsp[nt] += __shfl_xor(wsp[nt], 16, 64);
      wsp[nt] += __shfl_xor(wsp[nt], 32, 64);
    }
    if (qd == 0) {
#pragma unroll
      for (int nt = 0; nt < 2; ++nt)
        biasb[bh * T_ + tb + wave * 32 + nt * 16 + lr] = wsp[nt] / (256.f * ls[nt]);
    }
  } else {
    half_t* Qs  = smem;            // 128x64
    half_t* Ks  = smem + 8192;     // 64x64
    half_t* Vts = smem + 12288;    // 64x64
    const int idx = blockIdx.x - 512;
    const int bh = idx >> 4;
    const int qb = (idx & 15) * 128;
    const int b = bh >> 3, h = bh & 7;
#pragma unroll
    for (int j = 0; j < 4; ++j) {
      int row = wave * 32 + j * 8 + rr;
      gload_lds16(qkvx + (size_t)(b * T_ + qb + row) * 1024 + h * D_ + cs * 8,
                  Qs + (wave * 32 + j * 8) * 64);
    }
    __syncthreads();
    half8 qfA[2], qfB[2];
#pragma unroll
    for (int kc = 0; kc < 2; ++kc) {
      qfA[kc] = frag64(Qs, wave * 32 + lr, kc, qd);
      qfB[kc] = frag64(Qs, wave * 32 + 16 + lr, kc, qd);
    }
    floatx4 oA[4], oB[4], lacA, lacB;
#pragma unroll
    for (int dt = 0; dt < 4; ++dt)
#pragma unroll
      for (int r = 0; r < 4; ++r) { oA[dt][r] = 0.f; oB[dt][r] = 0.f; }
#pragma unroll
    for (int r = 0; r < 4; ++r) { lacA[r] = 0.f; lacB[r] = 0.f; }
    for (int kt = 0; kt < 4; ++kt) {
      const int kb = kt * 64;
      __syncthreads();
#pragma unroll
      for (int j = 0; j < 2; ++j) {
        int row = wave * 16 + j * 8 + rr;
        gload_lds16(qkvy + (size_t)(b * M_ + kb + row) * 1024 + C_ + h * D_ + cs * 8,
                    Ks + (wave * 16 + j * 8) * 64);
        gload_lds16(vTy + ((size_t)bh * 64 + row) * M_ + kb + cs * 8,
                    Vts + (wave * 16 + j * 8) * 64);
      }
      __syncthreads();
      attn_tile_dual<false, true, false, false>(Ks, Vts, nullptr, qfA, qfB,
                                                oA, lacA, oB, lacB, qd, lr, 0);
    }
    attn_store2(cval, oA, lacA, b, qb + wave * 32, h, qd, lr);
    attn_store2(cval, oB, lacB, b, qb + wave * 32 + 16, h, qd, lr);
  }
}

// ---------------------------------------------------------------------------
// Fused gate GEMMs + sigmoid + combine, 64x128 tiles, BK=64.
// z = sigmoid(sv@W1+b1)*cv + sigmoid(cv@W2+b2)*sv
// ---------------------------------------------------------------------------
__global__ __launch_bounds__(256) void gate_gemm64(
    const half_t* __restrict__ sv, const half_t* __restrict__ cv,
    const half_t* __restrict__ W1, const half_t* __restrict__ W2,
    const float* __restrict__ b1, const float* __restrict__ b2,
    half_t* __restrict__ z) {
  __shared__ __align__(16) half_t S1[64 * 64];
  __shared__ __align__(16) half_t S2[64 * 64];
  __shared__ __align__(16) half_t B1s[128 * 64];
  __shared__ __align__(16) half_t B2s[128 * 64];
  const int tid = threadIdx.x, lane = tid & 63, wave = tid >> 6;
  const int wm = wave >> 1, wn = wave & 1;
  const int rowBase = blockIdx.y * 64, colBase = blockIdx.x * 128;
  const int qd = lane >> 4, lr = lane & 15;
  const int rr = lane >> 3, cc = lane & 7;
  const int cs = cc ^ rr;

  floatx4 a1[2][4], a2[2][4];
#pragma unroll
  for (int mi = 0; mi < 2; ++mi)
#pragma unroll
    for (int ni = 0; ni < 4; ++ni)
#pragma unroll
      for (int r = 0; r < 4; ++r) { a1[mi][ni][r] = 0.f; a2[mi][ni][r] = 0.f; }

  for (int k0 = 0; k0 < 512; k0 += 64) {
    __syncthreads();
#pragma unroll
    for (int j = 0; j < 2; ++j) {
      int rA = wave * 16 + j * 8 + rr;
      gload_lds16(sv + (size_t)(rowBase + rA) * 512 + k0 + cs * 8, S1 + (wave * 16 + j * 8) * 64);
      gload_lds16(cv + (size_t)(rowBase + rA) * 512 + k0 + cs * 8, S2 + (wave * 16 + j * 8) * 64);
      gload_lds16(W1 + (size_t)(colBase + rA) * 512 + k0 + cs * 8, B1s + (wave * 16 + j * 8) * 64);
      gload_lds16(W1 + (size_t)(colBase + 64 + rA) * 512 + k0 + cs * 8, B1s + (64 + wave * 16 + j * 8) * 64);
      gload_lds16(W2 + (size_t)(colBase + rA) * 512 + k0 + cs * 8, B2s + (wave * 16 + j * 8) * 64);
      gload_lds16(W2 + (size_t)(colBase + 64 + rA) * 512 + k0 + cs * 8, B2s + (64 + wave * 16 + j * 8) * 64);
    }
    __syncthreads();
#pragma unroll
    for (int kc = 0; kc < 2; ++kc) {
      half8 af1[2], af2[2], bf1[4], bf2[4];
#pragma unroll
      for (int mi = 0; mi < 2; ++mi) {
        af1[mi] = frag64(S1, wm * 32 + mi * 16 + lr, kc, qd);
        af2[mi] = frag64(S2, wm * 32 + mi * 16 + lr, kc, qd);
      }
#pragma unroll
      for (int ni = 0; ni < 4; ++ni) {
        bf1[ni] = frag64(B1s, wn * 64 + ni * 16 + lr, kc, qd);
        bf2[ni] = frag64(B2s, wn * 64 + ni * 16 + lr, kc, qd);
      }
#pragma unroll
      for (int mi = 0; mi < 2; ++mi)
#pragma unroll
        for (int ni = 0; ni < 4; ++ni) {
          a1[mi][ni] = mfma16(af1[mi], bf1[ni], a1[mi][ni]);
          a2[mi][ni] = mfma16(af2[mi], bf2[ni], a2[mi][ni]);
        }
    }
  }

#pragma unroll
  for (int ni = 0; ni < 4; ++ni) {
    int col = colBase + wn * 64 + ni * 16 + lr;
    float g1b = b1[col], g2b = b2[col];
#pragma unroll
    for (int mi = 0; mi < 2; ++mi) {
      int row0 = rowBase + wm * 32 + mi * 16 + qd * 4;
#pragma unroll
      for (int r = 0; r < 4; ++r) {
        size_t idx = (size_t)(row0 + r) * 512 + col;
        float sg1 = 1.f / (1.f + __expf(-(a1[mi][ni][r] + g1b)));
        float sg2 = 1.f / (1.f + __expf(-(a2[mi][ni][r] + g2b)));
        z[idx] = (half_t)(sg1 * (float)cv[idx] + sg2 * (float)sv[idx]);
      }
    }
  }
}

// ---------------------------------------------------------------------------
// Final projection: out = z @ Wp^T + bp, fp32 out, 64x128 tiles, BK=64.
// ---------------------------------------------------------------------------
__global__ __launch_bounds__(256) void gemm_final64(
    const half_t* __restrict__ A, const half_t* __restrict__ Wt,
    const float* __restrict__ bias, float* __restrict__ Cout) {
  __shared__ __align__(16) half_t As[64 * 64];
  __shared__ __align__(16) half_t Bs[128 * 64];
  const int tid = threadIdx.x, lane = tid & 63, wave = tid >> 6;
  const int wm = wave >> 1, wn = wave & 1;
  const int rowBase = blockIdx.y * 64, colBase = blockIdx.x * 128;
  const int qd = lane >> 4, lr = lane & 15;
  const int rr = lane >> 3, cc = lane & 7;
  const int cs = cc ^ rr;

  floatx4 acc[2][4];
#pragma unroll
  for (int mi = 0; mi < 2; ++mi)
#pragma unroll
    for (int ni = 0; ni < 4; ++ni)
#pragma unroll
      for (int r = 0; r < 4; ++r) acc[mi][ni][r] = 0.f;

  for (int k0 = 0; k0 < 512; k0 += 64) {
    __syncthreads();
#pragma unroll
    for (int j = 0; j < 2; ++j) {
      int rA = wave * 16 + j * 8 + rr;
      gload_lds16(A + (size_t)(rowBase + rA) * 512 + k0 + cs * 8, As + (wave * 16 + j * 8) * 64);
      gload_lds16(Wt + (size_t)(colBase + rA) * 512 + k0 + cs * 8, Bs + (wave * 16 + j * 8) * 64);
      gload_lds16(Wt + (size_t)(colBase + 64 + rA) * 512 + k0 + cs * 8, Bs + (64 + wave * 16 + j * 8) * 64);
    }
    __syncthreads();
#pragma unroll
    for (int kc = 0; kc < 2; ++kc) {
      half8 af[2], bf[4];
#pragma unroll
      for (int mi = 0; mi < 2; ++mi) af[mi] = frag64(As, wm * 32 + mi * 16 + lr, kc, qd);
#pragma unroll
      for (int ni = 0; ni < 4; ++ni) bf[ni] = frag64(Bs, wn * 64 + ni * 16 + lr, kc, qd);
#pragma unroll
      for (int mi = 0; mi < 2; ++mi)
#pragma unroll
        for (int ni = 0; ni < 4; ++ni)
          acc[mi][ni] = mfma16(af[mi], bf[ni], acc[mi][ni]);
    }
  }

#pragma unroll
  for (int ni = 0; ni < 4; ++ni) {
    int col = colBase + wn * 64 + ni * 16 + lr;
    float bc = bias[col];
#pragma unroll
    for (int mi = 0; mi < 2; ++mi) {
      int row0 = rowBase + wm * 32 + mi * 16 + qd * 4;
#pragma unroll
      for (int r = 0; r < 4; ++r)
        Cout[(size_t)(row0 + r) * 512 + col] = acc[mi][ni][r] + bc;
    }
  }
}

// ---------------------------------------------------------------------------
extern "C" void kernel_launch(void* const* d_in, const int* in_sizes, int n_in,
                              void* d_out, int out_size, void* d_ws, size_t ws_size,
                              hipStream_t stream) {
  (void)in_sizes; (void)n_in; (void)out_size; (void)ws_size;
  const float* x      = (const float*)d_in[0];
  const float* y      = (const float*)d_in[1];
  const float* Wqkv_x = (const float*)d_in[3];
  const float* bqkv_x = (const float*)d_in[4];
  const float* Wqkv_y = (const float*)d_in[5];
  const float* bqkv_y = (const float*)d_in[6];
  const float* Wgs    = (const float*)d_in[7];
  const float* bgs    = (const float*)d_in[8];
  const float* Wgc    = (const float*)d_in[9];
  const float* bgc    = (const float*)d_in[10];
  const float* Wp     = (const float*)d_in[11];
  const float* bp     = (const float*)d_in[12];
  float* out = (float*)d_out;

  half_t* h = (half_t*)d_ws;
  half_t* x16    = h;  h += (size_t)B_ * T_ * C_;
  half_t* y16    = h;  h += (size_t)B_ * M_ * C_;
  half_t* WqkvxT = h;  h += (size_t)TC3 * C_;
  half_t* WqkvyT = h;  h += (size_t)TC3 * C_;
  half_t* WgsT   = h;  h += (size_t)C_ * C_;
  half_t* WgcT   = h;  h += (size_t)C_ * C_;
  half_t* WpT    = h;  h += (size_t)C_ * C_;
  half_t* qkvx   = h;  h += (size_t)B_ * T_ * 1024;
  half_t* qkvy   = h;  h += (size_t)B_ * M_ * 1024;
  half_t* vTx    = h;  h += (size_t)B_ * C_ * T_;
  half_t* vTy    = h;  h += (size_t)B_ * C_ * M_;
  half_t* sval   = h;  h += (size_t)B_ * T_ * C_;
  half_t* cval   = h;  h += (size_t)B_ * T_ * C_;
  half_t* z      = h;  h += (size_t)B_ * T_ * C_;
  float* biasb   = (float*)h;

  conv_all<<<3456, 256, 0, stream>>>(x, x16, y, y16,
                                     Wqkv_x, Wqkv_y, Wgs, Wgc, Wp,
                                     WqkvxT, WqkvyT, WgsT, WgcT, WpT);

  gemm_qkvt<<<864, 256, 0, stream>>>(x16, y16, WqkvxT, WqkvyT,
                                     bqkv_x, bqkv_y, qkvx, qkvy, vTx, vTy);

  bias_cross<<<1024, 256, 0, stream>>>(qkvx, qkvy, vTy, biasb, cval);

  self_attn_reg<<<512, 256, 0, stream>>>(qkvx, vTx, biasb, sval);

  gate_gemm64<<<dim3(4, 128), 256, 0, stream>>>(sval, cval, WgsT, WgcT, bgs, bgc, z);

  gemm_final64<<<dim3(4, 128), 256, 0, stream>>>(z, WpT, bp, out);
}

// Round 11
// 224.169 us; speedup vs baseline: 1.0761x; 1.0761x over previous
//
#include <hip/hip_runtime.h>
#include <hip/hip_bf16.h>
#include <math.h>

// Problem constants (B,T,M,C,H = 4,2048,256,512,8; D=64)
#define B_ 4
#define T_ 2048
#define M_ 256
#define C_ 512
#define H_ 8
#define D_ 64
#define TC3 1536
// 1/sqrt(64) * log2(e): folded into Q so all softmax exps are bare v_exp_f32
#define QSCALE2 0.18033688f

typedef _Float16 half_t;
typedef _Float16 half8 __attribute__((ext_vector_type(8)));
typedef _Float16 half4 __attribute__((ext_vector_type(4)));
typedef float floatx4 __attribute__((ext_vector_type(4)));

// bare v_exp_f32 (2^x) — NOT libm exp2f (which expands to a slow precise seq)
__device__ __forceinline__ float fexp2(float x) { return __builtin_amdgcn_exp2f(x); }

// ---- async global->LDS, 16B per lane; lane i lands at ldsbase + i*16B.
// One 64-lane call stages 1024 B = 8 rows of a 64-half (128 B) tile.
__device__ __forceinline__ void gload_lds16(const half_t* g, half_t* lds) {
  __builtin_amdgcn_global_load_lds(
      (const __attribute__((address_space(1))) unsigned int*)g,
      (__attribute__((address_space(3))) unsigned int*)(unsigned)(unsigned long long)(void*)lds,
      16, 0, 0);
}

__device__ __forceinline__ floatx4 mfma16(half8 a, half8 b, floatx4 c) {
  return __builtin_amdgcn_mfma_f32_16x16x32_f16(a, b, c, 0, 0, 0);
}
__device__ __forceinline__ floatx4 mfma16k16(half4 a, half4 b, floatx4 c) {
  return __builtin_amdgcn_mfma_f32_16x16x16f16(a, b, c, 0, 0, 0);
}

// Swizzled LDS tiles: 64-half rows, 8 chunks of 8 halves; slot = chunk ^ (row&7)
__device__ __forceinline__ half8 frag64(const half_t* lds, int row, int kc, int quad) {
  int slot = ((kc << 2) + quad) ^ (row & 7);
  return *(const half8*)(lds + row * 64 + slot * 8);
}

// ---------------------------------------------------------------------------
// Fused conversions: blocks [0,2304) transpose 5 weight mats fp32->fp16
// k-major; blocks [2304,3456) convert x,y fp32->fp16.
// ---------------------------------------------------------------------------
__global__ __launch_bounds__(256) void conv_all(
    const float* x, half_t* xo, const float* y, half_t* yo,
    const float* w0, const float* w1, const float* w2, const float* w3, const float* w4,
    half_t* o0, half_t* o1, half_t* o2, half_t* o3, half_t* o4) {
  __shared__ float tile[32][33];
  const int tid = threadIdx.x;
  if (blockIdx.x < 2304) {
    int blk = blockIdx.x;
    const float* src; half_t* dst; int N;
    if (blk < 768)       { src = w0; dst = o0; N = 1536; }
    else if (blk < 1536) { src = w1; dst = o1; N = 1536; blk -= 768; }
    else if (blk < 1792) { src = w2; dst = o2; N = 512;  blk -= 1536; }
    else if (blk < 2048) { src = w3; dst = o3; N = 512;  blk -= 1792; }
    else                 { src = w4; dst = o4; N = 512;  blk -= 2048; }
    const int ntx = N >> 5;
    const int tk = blk / ntx, tn = blk % ntx;
    const int r = tid >> 3, c = (tid & 7) * 4;
    float4 v = *(const float4*)(src + (size_t)(tk * 32 + r) * N + tn * 32 + c);
    tile[r][c] = v.x; tile[r][c + 1] = v.y; tile[r][c + 2] = v.z; tile[r][c + 3] = v.w;
    __syncthreads();
    half4 h;
#pragma unroll
    for (int j = 0; j < 4; ++j) h[j] = (half_t)tile[c + j][r];
    *(half4*)(dst + (size_t)(tn * 32 + r) * 512 + tk * 32 + c) = h;
  } else {
    const int nx = B_ * T_ * C_, ny = B_ * M_ * C_;
    const int n4x = nx >> 2, tot = n4x + (ny >> 2);
    int i = (blockIdx.x - 2304) * 256 + tid;
    const int stride = (gridDim.x - 2304) * 256;
    for (; i < tot; i += stride) {
      const float4* s; half_t* d; int idx;
      if (i < n4x) { s = (const float4*)x; d = xo; idx = i; }
      else { s = (const float4*)y; d = yo; idx = i - n4x; }
      float4 v = s[idx];
      half4 h; h[0] = (half_t)v.x; h[1] = (half_t)v.y; h[2] = (half_t)v.z; h[3] = (half_t)v.w;
      *(half4*)(d + idx * 4) = h;
    }
  }
}

// ---------------------------------------------------------------------------
// GEMM core: 128x128, K=512, BK=64.
// ---------------------------------------------------------------------------
struct GemmAcc { floatx4 a[4][4]; };

__device__ __forceinline__ void gemm_core64(
    const half_t* __restrict__ A, const half_t* __restrict__ Wt,
    int rowBase, int colBase, GemmAcc& g,
    half_t* As, half_t* Bs, int tid) {
  const int lane = tid & 63, wave = tid >> 6;
  const int wm = wave >> 1, wn = wave & 1;
  const int qd = lane >> 4, lr = lane & 15;
  const int rr = lane >> 3, cc = lane & 7;
  const int cs = cc ^ rr;
#pragma unroll
  for (int mi = 0; mi < 4; ++mi)
#pragma unroll
    for (int ni = 0; ni < 4; ++ni)
#pragma unroll
      for (int r = 0; r < 4; ++r) g.a[mi][ni][r] = 0.f;
  for (int k0 = 0; k0 < 512; k0 += 64) {
    __syncthreads();
#pragma unroll
    for (int j = 0; j < 4; ++j) {
      int row = wave * 32 + j * 8 + rr;
      gload_lds16(A + (size_t)(rowBase + row) * 512 + k0 + cs * 8, As + (wave * 32 + j * 8) * 64);
      gload_lds16(Wt + (size_t)(colBase + row) * 512 + k0 + cs * 8, Bs + (wave * 32 + j * 8) * 64);
    }
    __syncthreads();
#pragma unroll
    for (int kc = 0; kc < 2; ++kc) {
      half8 af[4], bf[4];
#pragma unroll
      for (int mi = 0; mi < 4; ++mi) af[mi] = frag64(As, wm * 64 + mi * 16 + lr, kc, qd);
#pragma unroll
      for (int ni = 0; ni < 4; ++ni) bf[ni] = frag64(Bs, wn * 64 + ni * 16 + lr, kc, qd);
#pragma unroll
      for (int mi = 0; mi < 4; ++mi)
#pragma unroll
        for (int ni = 0; ni < 4; ++ni)
          g.a[mi][ni] = mfma16(af[mi], bf[ni], g.a[mi][ni]);
    }
  }
}

// ---------------------------------------------------------------------------
// Fused QK + V^T projections. Blocks [0,576): QK for x,y (Q cols pre-scaled
// by QSCALE2 = 0.125*log2e). Blocks [576,864): vT = Wv^T @ x^T (+row bias).
// ---------------------------------------------------------------------------
__global__ __launch_bounds__(256) void gemm_qkvt(
    const half_t* __restrict__ x16, const half_t* __restrict__ y16,
    const half_t* __restrict__ WxT, const half_t* __restrict__ WyT,
    const float* __restrict__ bqx, const float* __restrict__ bqy,
    half_t* __restrict__ qkvx, half_t* __restrict__ qkvy,
    half_t* __restrict__ vTx, half_t* __restrict__ vTy) {
  __shared__ __align__(16) half_t As[128 * 64];
  __shared__ __align__(16) half_t Bs[128 * 64];
  const int tid = threadIdx.x, lane = tid & 63, wave = tid >> 6;
  const int wm = wave >> 1, wn = wave & 1;
  const int qd = lane >> 4, lr = lane & 15;
  const int bxi = blockIdx.x;
  const half_t* A; const half_t* Wt; const float* bias; half_t* out;
  int rowBase, colBase, N; bool vt;
  if (bxi < 576) {
    vt = false; N = 1024;
    colBase = (bxi & 7) * 128;
    int ry = bxi >> 3;
    if (ry < 64) { A = x16; Wt = WxT; bias = bqx; out = qkvx; rowBase = ry * 128; }
    else { A = y16; Wt = WyT; bias = bqy; out = qkvy; rowBase = (ry - 64) * 128; }
  } else {
    vt = true;
    int i = bxi - 576;
    int xx = i % 18; int rest = i / 18;
    int yy = rest & 3, zz = rest >> 2;
    rowBase = yy * 128;
    if (xx < 16) {
      A = WxT + (size_t)1024 * 512; Wt = x16 + (size_t)zz * T_ * C_; bias = bqx + 1024;
      out = vTx + (size_t)zz * C_ * T_; N = T_; colBase = xx * 128;
    } else {
      A = WyT + (size_t)1024 * 512; Wt = y16 + (size_t)zz * M_ * C_; bias = bqy + 1024;
      out = vTy + (size_t)zz * C_ * M_; N = M_; colBase = (xx - 16) * 128;
    }
  }
  GemmAcc g;
  gemm_core64(A, Wt, rowBase, colBase, g, As, Bs, tid);
  if (!vt) {
#pragma unroll
    for (int ni = 0; ni < 4; ++ni) {
      int col = colBase + wn * 64 + ni * 16 + lr;
      float csc = (col < 512) ? QSCALE2 : 1.f;
      float bc = bias[col];
#pragma unroll
      for (int mi = 0; mi < 4; ++mi) {
        int row0 = rowBase + wm * 64 + mi * 16 + qd * 4;
#pragma unroll
        for (int r = 0; r < 4; ++r)
          out[(size_t)(row0 + r) * 1024 + col] = (half_t)((g.a[mi][ni][r] + bc) * csc);
      }
    }
  } else {
#pragma unroll
    for (int ni = 0; ni < 4; ++ni) {
      int col = colBase + wn * 64 + ni * 16 + lr;
#pragma unroll
      for (int mi = 0; mi < 4; ++mi) {
        int row0 = rowBase + wm * 64 + mi * 16 + qd * 4;
#pragma unroll
        for (int r = 0; r < 4; ++r)
          out[(size_t)(row0 + r) * N + col] = (half_t)(g.a[mi][ni][r] + bias[row0 + r]);
      }
    }
  }
}

// ---------------------------------------------------------------------------
// Dual-group attention tile (log2-domain softmax via bare v_exp_f32):
// groups A/B share K/V fragment reads; row-sum l via ones-column MFMA.
// ---------------------------------------------------------------------------
template <bool USE_BIAS, bool DO_A, bool DIAG_A, bool DIAG_B>
__device__ __forceinline__ void attn_tile_dual(
    const half_t* __restrict__ Ks, const half_t* __restrict__ Vts,
    const float* __restrict__ Bsh, const half8* qfA, const half8* qfB,
    floatx4* oA, floatx4& lacA, floatx4* oB, floatx4& lacB,
    int qd, int lr, int thresh) {
  floatx4 sA[4], sB[4];
#pragma unroll
  for (int ks = 0; ks < 4; ++ks)
#pragma unroll
    for (int r = 0; r < 4; ++r) { sA[ks][r] = 0.f; sB[ks][r] = 0.f; }
#pragma unroll
  for (int kc = 0; kc < 2; ++kc) {
#pragma unroll
    for (int ks = 0; ks < 4; ++ks) {
      half8 kfr = frag64(Ks, ks * 16 + lr, kc, qd);
      if (DO_A) sA[ks] = mfma16(kfr, qfA[kc], sA[ks]);
      sB[ks] = mfma16(kfr, qfB[kc], sB[ks]);
    }
  }
  half4 pA[4], pB[4];
#pragma unroll
  for (int ks = 0; ks < 4; ++ks) {
    floatx4 bf;
    if (USE_BIAS) bf = *(const floatx4*)(Bsh + ks * 16 + qd * 4);
#pragma unroll
    for (int r = 0; r < 4; ++r) {
      int keyl = ks * 16 + qd * 4 + r;
      if (DO_A) {
        float t = USE_BIAS ? (sA[ks][r] + bf[r]) : sA[ks][r];
        float p1 = fexp2(t);
        if (DIAG_A && keyl > thresh) p1 = 0.f;
        pA[ks][r] = (half_t)p1;
      }
      float t2 = USE_BIAS ? (sB[ks][r] + bf[r]) : sB[ks][r];
      float p2 = fexp2(t2);
      if (DIAG_B && keyl > thresh) p2 = 0.f;
      pB[ks][r] = (half_t)p2;
    }
  }
  const half4 ones4 = {(half_t)1.f, (half_t)1.f, (half_t)1.f, (half_t)1.f};
#pragma unroll
  for (int ks = 0; ks < 4; ++ks) {
    int slot = (ks * 2 + (qd >> 1)) ^ (lr & 7);
    const half_t* vbase = Vts + slot * 8 + (qd & 1) * 4;
#pragma unroll
    for (int dt = 0; dt < 4; ++dt) {
      half4 vf = *(const half4*)(vbase + (dt * 16 + lr) * 64);
      if (DO_A) oA[dt] = mfma16k16(pA[ks], vf, oA[dt]);
      oB[dt] = mfma16k16(pB[ks], vf, oB[dt]);
    }
    if (DO_A) lacA = mfma16k16(pA[ks], ones4, lacA);
    lacB = mfma16k16(pB[ks], ones4, lacB);
  }
}

// runtime flag dispatch for one 64-key tile of the causal loop
__device__ __forceinline__ void attn_step(
    int kt, int p, int ktEnd,
    const half_t* Ks, const half_t* Vts, const float* Bsh,
    const half8* qfA, const half8* qfB,
    floatx4* oA, floatx4& lacA, floatx4* oB, floatx4& lacB,
    int qd, int lr, int thresh) {
  if (kt < p)
    attn_tile_dual<true, true, false, false>(Ks, Vts, Bsh, qfA, qfB, oA, lacA, oB, lacB, qd, lr, thresh);
  else if (kt == p)
    attn_tile_dual<true, true, true, false>(Ks, Vts, Bsh, qfA, qfB, oA, lacA, oB, lacB, qd, lr, thresh);
  else if (kt < ktEnd)
    attn_tile_dual<true, false, false, false>(Ks, Vts, Bsh, qfA, qfB, oA, lacA, oB, lacB, qd, lr, thresh);
  else
    attn_tile_dual<true, false, false, true>(Ks, Vts, Bsh, qfA, qfB, oA, lacA, oB, lacB, qd, lr, thresh);
}

__device__ __forceinline__ void attn_store2(
    half_t* __restrict__ dst, const floatx4* o, floatx4 lac,
    int b, int qbase, int h, int qd, int lr) {
  floatx4 inv;
#pragma unroll
  for (int r = 0; r < 4; ++r) inv[r] = 1.f / lac[r];
#pragma unroll
  for (int dt = 0; dt < 4; ++dt)
#pragma unroll
    for (int r = 0; r < 4; ++r)
      dst[(size_t)(b * T_ + qbase + qd * 4 + r) * C_ + h * D_ + dt * 16 + lr] =
          (half_t)(o[dt][r] * inv[r]);
}

// ---------------------------------------------------------------------------
// Balanced causal self-attention (r4 structure): block = (bh,p) pair
// (p, 31-p); wave = 16q-low (A) + 16q-high (B); 1 k-tile per barrier.
// 33 KB LDS -> 4 blocks/CU.
// ---------------------------------------------------------------------------
__global__ __launch_bounds__(256) void self_attn_reg(
    const half_t* __restrict__ qkv, const half_t* __restrict__ vT,
    const float* __restrict__ biasb, half_t* __restrict__ sval) {
  __shared__ __align__(16) half_t Qs[128 * 64];
  __shared__ __align__(16) half_t Ks[64 * 64];
  __shared__ __align__(16) half_t Vts[64 * 64];
  __shared__ __align__(16) float Bsh[64];
  const int tid = threadIdx.x, lane = tid & 63, wave = tid >> 6;
  const int p = blockIdx.x & 15;
  const int bh = blockIdx.x >> 4;
  const int b = bh >> 3, h = bh & 7;
  const int qbL = p * 64, qbH = (31 - p) * 64;
  const int qd = lane >> 4, lr = lane & 15;
  const int rr = lane >> 3, cc = lane & 7;
  const int cs = cc ^ rr;

  // stage Q: rows 0..63 = low tile, 64..127 = high tile
#pragma unroll
  for (int j = 0; j < 4; ++j) {
    int rowIdx = wave * 32 + j * 8 + rr;
    int grow = (rowIdx < 64) ? (qbL + rowIdx) : (qbH + rowIdx - 64);
    gload_lds16(qkv + (size_t)(b * T_ + grow) * 1024 + h * D_ + cs * 8,
                Qs + (wave * 32 + j * 8) * 64);
  }
  __syncthreads();
  half8 qfA[2], qfB[2];
#pragma unroll
  for (int kc = 0; kc < 2; ++kc) {
    qfA[kc] = frag64(Qs, wave * 16 + lr, kc, qd);
    qfB[kc] = frag64(Qs, 64 + wave * 16 + lr, kc, qd);
  }
  floatx4 oA[4], oB[4], lacA, lacB;
#pragma unroll
  for (int dt = 0; dt < 4; ++dt)
#pragma unroll
    for (int r = 0; r < 4; ++r) { oA[dt][r] = 0.f; oB[dt][r] = 0.f; }
#pragma unroll
  for (int r = 0; r < 4; ++r) { lacA[r] = 0.f; lacB[r] = 0.f; }
  const int thresh = wave * 16 + lr;
  const int ktEnd = 31 - p;

  for (int kt = 0; kt <= ktEnd; ++kt) {
    const int kb = kt * 64;
    __syncthreads();
#pragma unroll
    for (int j = 0; j < 2; ++j) {
      int row = wave * 16 + j * 8 + rr;
      gload_lds16(qkv + (size_t)(b * T_ + kb + row) * 1024 + C_ + h * D_ + cs * 8,
                  Ks + (wave * 16 + j * 8) * 64);
      gload_lds16(vT + ((size_t)bh * 64 + row) * T_ + kb + cs * 8,
                  Vts + (wave * 16 + j * 8) * 64);
    }
    if (tid < 64) Bsh[tid] = biasb[bh * T_ + kb + tid];
    __syncthreads();
    attn_step(kt, p, ktEnd, Ks, Vts, Bsh, qfA, qfB, oA, lacA, oB, lacB, qd, lr, thresh);
  }
  attn_store2(sval, oA, lacA, b, qbL + wave * 16, h, qd, lr);
  attn_store2(sval, oB, lacB, b, qbH + wave * 16, h, qd, lr);
}

// ---------------------------------------------------------------------------
// Fused bias + cross-attention, 32 KB LDS (5 blocks/CU).
// Blocks [0,512): per-key bias (log2 domain), Qy staged in 2 chunks of 128.
// Blocks [512,1024): cross-attn x->y, 1 k-tile/barrier.
// ---------------------------------------------------------------------------
__global__ __launch_bounds__(256) void bias_cross(
    const half_t* __restrict__ qkvx, const half_t* __restrict__ qkvy,
    const half_t* __restrict__ vTy, float* __restrict__ biasb,
    half_t* __restrict__ cval) {
  __shared__ __align__(16) half_t smem[16384];   // 32 KB
  const int tid = threadIdx.x, lane = tid & 63, wave = tid >> 6;
  const int qd = lane >> 4, lr = lane & 15;
  const int rr = lane >> 3, cc = lane & 7;
  const int cs = cc ^ rr;
  if (blockIdx.x < 512) {
    half_t* Qy = smem;            // 128x64 chunk
    half_t* Kx = smem + 8192;     // 128x64
    const int bh = blockIdx.x >> 4;
    const int tb = (blockIdx.x & 15) * 128;
    const int b = bh >> 3, h = bh & 7;
    // stage Kx + Qy chunk 0
#pragma unroll
    for (int j = 0; j < 4; ++j) {
      int r = wave * 32 + j * 8 + rr;
      gload_lds16(qkvx + (size_t)(b * T_ + tb + r) * 1024 + C_ + h * D_ + cs * 8,
                  Kx + (wave * 32 + j * 8) * 64);
      gload_lds16(qkvy + (size_t)(b * M_ + r) * 1024 + h * D_ + cs * 8,
                  Qy + (wave * 32 + j * 8) * 64);
    }
    __syncthreads();
    half8 kf[2][2];
#pragma unroll
    for (int nt = 0; nt < 2; ++nt)
#pragma unroll
      for (int kc = 0; kc < 2; ++kc)
        kf[nt][kc] = frag64(Kx, wave * 32 + nt * 16 + lr, kc, qd);
    float ls[2] = {0.f, 0.f}, wsp[2] = {0.f, 0.f};
    for (int chunk = 0; chunk < 2; ++chunk) {
      if (chunk) {
        __syncthreads();   // all waves done reading chunk 0
#pragma unroll
        for (int j = 0; j < 4; ++j) {
          int r = wave * 32 + j * 8 + rr;
          gload_lds16(qkvy + (size_t)(b * M_ + 128 + r) * 1024 + h * D_ + cs * 8,
                      Qy + (wave * 32 + j * 8) * 64);
        }
        __syncthreads();
      }
      for (int mt = 0; mt < 8; ++mt) {
        half8 af[2];
#pragma unroll
        for (int kc = 0; kc < 2; ++kc) af[kc] = frag64(Qy, mt * 16 + lr, kc, qd);
#pragma unroll
        for (int nt = 0; nt < 2; ++nt) {
          floatx4 s;
#pragma unroll
          for (int r = 0; r < 4; ++r) s[r] = 0.f;
#pragma unroll
          for (int kc = 0; kc < 2; ++kc) s = mfma16(af[kc], kf[nt][kc], s);
#pragma unroll
          for (int r = 0; r < 4; ++r) {
            float e = fexp2(s[r]);
            ls[nt] += e;
            wsp[nt] += e * s[r];
          }
        }
      }
    }
#pragma unroll
    for (int nt = 0; nt < 2; ++nt) {
      ls[nt] += __shfl_xor(ls[nt], 16, 64);
      ls[nt] += __shfl_xor(ls[nt], 32, 64);
      wsp[nt] += __shfl_xor(wsp[nt], 16, 64);
      wsp[nt] += __shfl_xor(wsp[nt], 32, 64);
    }
    if (qd == 0) {
#pragma unroll
      for (int nt = 0; nt < 2; ++nt)
        biasb[bh * T_ + tb + wave * 32 + nt * 16 + lr] = wsp[nt] / (256.f * ls[nt]);
    }
  } else {
    half_t* Qs  = smem;            // 128x64
    half_t* Ks  = smem + 8192;     // 64x64
    half_t* Vts = smem + 12288;    // 64x64
    const int idx = blockIdx.x - 512;
    const int bh = idx >> 4;
    const int qb = (idx & 15) * 128;
    const int b = bh >> 3, h = bh & 7;
#pragma unroll
    for (int j = 0; j < 4; ++j) {
      int row = wave * 32 + j * 8 + rr;
      gload_lds16(qkvx + (size_t)(b * T_ + qb + row) * 1024 + h * D_ + cs * 8,
                  Qs + (wave * 32 + j * 8) * 64);
    }
    __syncthreads();
    half8 qfA[2], qfB[2];
#pragma unroll
    for (int kc = 0; kc < 2; ++kc) {
      qfA[kc] = frag64(Qs, wave * 32 + lr, kc, qd);
      qfB[kc] = frag64(Qs, wave * 32 + 16 + lr, kc, qd);
    }
    floatx4 oA[4], oB[4], lacA, lacB;
#pragma unroll
    for (int dt = 0; dt < 4; ++dt)
#pragma unroll
      for (int r = 0; r < 4; ++r) { oA[dt][r] = 0.f; oB[dt][r] = 0.f; }
#pragma unroll
    for (int r = 0; r < 4; ++r) { lacA[r] = 0.f; lacB[r] = 0.f; }
    for (int kt = 0; kt < 4; ++kt) {
      const int kb = kt * 64;
      __syncthreads();
#pragma unroll
      for (int j = 0; j < 2; ++j) {
        int row = wave * 16 + j * 8 + rr;
        gload_lds16(qkvy + (size_t)(b * M_ + kb + row) * 1024 + C_ + h * D_ + cs * 8,
                    Ks + (wave * 16 + j * 8) * 64);
        gload_lds16(vTy + ((size_t)bh * 64 + row) * M_ + kb + cs * 8,
                    Vts + (wave * 16 + j * 8) * 64);
      }
      __syncthreads();
      attn_tile_dual<false, true, false, false>(Ks, Vts, nullptr, qfA, qfB,
                                                oA, lacA, oB, lacB, qd, lr, 0);
    }
    attn_store2(cval, oA, lacA, b, qb + wave * 32, h, qd, lr);
    attn_store2(cval, oB, lacB, b, qb + wave * 32 + 16, h, qd, lr);
  }
}

// ---------------------------------------------------------------------------
// Fused gate GEMMs + sigmoid + combine, 64x128 tiles, BK=64.
// z = sigmoid(sv@W1+b1)*cv + sigmoid(cv@W2+b2)*sv
// ---------------------------------------------------------------------------
__global__ __launch_bounds__(256) void gate_gemm64(
    const half_t* __restrict__ sv, const half_t* __restrict__ cv,
    const half_t* __restrict__ W1, const half_t* __restrict__ W2,
    const float* __restrict__ b1, const float* __restrict__ b2,
    half_t* __restrict__ z) {
  __shared__ __align__(16) half_t S1[64 * 64];
  __shared__ __align__(16) half_t S2[64 * 64];
  __shared__ __align__(16) half_t B1s[128 * 64];
  __shared__ __align__(16) half_t B2s[128 * 64];
  const int tid = threadIdx.x, lane = tid & 63, wave = tid >> 6;
  const int wm = wave >> 1, wn = wave & 1;
  const int rowBase = blockIdx.y * 64, colBase = blockIdx.x * 128;
  const int qd = lane >> 4, lr = lane & 15;
  const int rr = lane >> 3, cc = lane & 7;
  const int cs = cc ^ rr;

  floatx4 a1[2][4], a2[2][4];
#pragma unroll
  for (int mi = 0; mi < 2; ++mi)
#pragma unroll
    for (int ni = 0; ni < 4; ++ni)
#pragma unroll
      for (int r = 0; r < 4; ++r) { a1[mi][ni][r] = 0.f; a2[mi][ni][r] = 0.f; }

  for (int k0 = 0; k0 < 512; k0 += 64) {
    __syncthreads();
#pragma unroll
    for (int j = 0; j < 2; ++j) {
      int rA = wave * 16 + j * 8 + rr;
      gload_lds16(sv + (size_t)(rowBase + rA) * 512 + k0 + cs * 8, S1 + (wave * 16 + j * 8) * 64);
      gload_lds16(cv + (size_t)(rowBase + rA) * 512 + k0 + cs * 8, S2 + (wave * 16 + j * 8) * 64);
      gload_lds16(W1 + (size_t)(colBase + rA) * 512 + k0 + cs * 8, B1s + (wave * 16 + j * 8) * 64);
      gload_lds16(W1 + (size_t)(colBase + 64 + rA) * 512 + k0 + cs * 8, B1s + (64 + wave * 16 + j * 8) * 64);
      gload_lds16(W2 + (size_t)(colBase + rA) * 512 + k0 + cs * 8, B2s + (wave * 16 + j * 8) * 64);
      gload_lds16(W2 + (size_t)(colBase + 64 + rA) * 512 + k0 + cs * 8, B2s + (64 + wave * 16 + j * 8) * 64);
    }
    __syncthreads();
#pragma unroll
    for (int kc = 0; kc < 2; ++kc) {
      half8 af1[2], af2[2], bf1[4], bf2[4];
#pragma unroll
      for (int mi = 0; mi < 2; ++mi) {
        af1[mi] = frag64(S1, wm * 32 + mi * 16 + lr, kc, qd);
        af2[mi] = frag64(S2, wm * 32 + mi * 16 + lr, kc, qd);
      }
#pragma unroll
      for (int ni = 0; ni < 4; ++ni) {
        bf1[ni] = frag64(B1s, wn * 64 + ni * 16 + lr, kc, qd);
        bf2[ni] = frag64(B2s, wn * 64 + ni * 16 + lr, kc, qd);
      }
#pragma unroll
      for (int mi = 0; mi < 2; ++mi)
#pragma unroll
        for (int ni = 0; ni < 4; ++ni) {
          a1[mi][ni] = mfma16(af1[mi], bf1[ni], a1[mi][ni]);
          a2[mi][ni] = mfma16(af2[mi], bf2[ni], a2[mi][ni]);
        }
    }
  }

#pragma unroll
  for (int ni = 0; ni < 4; ++ni) {
    int col = colBase + wn * 64 + ni * 16 + lr;
    float g1b = b1[col], g2b = b2[col];
#pragma unroll
    for (int mi = 0; mi < 2; ++mi) {
      int row0 = rowBase + wm * 32 + mi * 16 + qd * 4;
#pragma unroll
      for (int r = 0; r < 4; ++r) {
        size_t idx = (size_t)(row0 + r) * 512 + col;
        float sg1 = 1.f / (1.f + __expf(-(a1[mi][ni][r] + g1b)));
        float sg2 = 1.f / (1.f + __expf(-(a2[mi][ni][r] + g2b)));
        z[idx] = (half_t)(sg1 * (float)cv[idx] + sg2 * (float)sv[idx]);
      }
    }
  }
}

// ---------------------------------------------------------------------------
// Final projection: out = z @ Wp^T + bp, fp32 out, 64x128 tiles, BK=64.
// ---------------------------------------------------------------------------
__global__ __launch_bounds__(256) void gemm_final64(
    const half_t* __restrict__ A, const half_t* __restrict__ Wt,
    const float* __restrict__ bias, float* __restrict__ Cout) {
  __shared__ __align__(16) half_t As[64 * 64];
  __shared__ __align__(16) half_t Bs[128 * 64];
  const int tid = threadIdx.x, lane = tid & 63, wave = tid >> 6;
  const int wm = wave >> 1, wn = wave & 1;
  const int rowBase = blockIdx.y * 64, colBase = blockIdx.x * 128;
  const int qd = lane >> 4, lr = lane & 15;
  const int rr = lane >> 3, cc = lane & 7;
  const int cs = cc ^ rr;

  floatx4 acc[2][4];
#pragma unroll
  for (int mi = 0; mi < 2; ++mi)
#pragma unroll
    for (int ni = 0; ni < 4; ++ni)
#pragma unroll
      for (int r = 0; r < 4; ++r) acc[mi][ni][r] = 0.f;

  for (int k0 = 0; k0 < 512; k0 += 64) {
    __syncthreads();
#pragma unroll
    for (int j = 0; j < 2; ++j) {
      int rA = wave * 16 + j * 8 + rr;
      gload_lds16(A + (size_t)(rowBase + rA) * 512 + k0 + cs * 8, As + (wave * 16 + j * 8) * 64);
      gload_lds16(Wt + (size_t)(colBase + rA) * 512 + k0 + cs * 8, Bs + (wave * 16 + j * 8) * 64);
      gload_lds16(Wt + (size_t)(colBase + 64 + rA) * 512 + k0 + cs * 8, Bs + (64 + wave * 16 + j * 8) * 64);
    }
    __syncthreads();
#pragma unroll
    for (int kc = 0; kc < 2; ++kc) {
      half8 af[2], bf[4];
#pragma unroll
      for (int mi = 0; mi < 2; ++mi) af[mi] = frag64(As, wm * 32 + mi * 16 + lr, kc, qd);
#pragma unroll
      for (int ni = 0; ni < 4; ++ni) bf[ni] = frag64(Bs, wn * 64 + ni * 16 + lr, kc, qd);
#pragma unroll
      for (int mi = 0; mi < 2; ++mi)
#pragma unroll
        for (int ni = 0; ni < 4; ++ni)
          acc[mi][ni] = mfma16(af[mi], bf[ni], acc[mi][ni]);
    }
  }

#pragma unroll
  for (int ni = 0; ni < 4; ++ni) {
    int col = colBase + wn * 64 + ni * 16 + lr;
    float bc = bias[col];
#pragma unroll
    for (int mi = 0; mi < 2; ++mi) {
      int row0 = rowBase + wm * 32 + mi * 16 + qd * 4;
#pragma unroll
      for (int r = 0; r < 4; ++r)
        Cout[(size_t)(row0 + r) * 512 + col] = acc[mi][ni][r] + bc;
    }
  }
}

// ---------------------------------------------------------------------------
extern "C" void kernel_launch(void* const* d_in, const int* in_sizes, int n_in,
                              void* d_out, int out_size, void* d_ws, size_t ws_size,
                              hipStream_t stream) {
  (void)in_sizes; (void)n_in; (void)out_size; (void)ws_size;
  const float* x      = (const float*)d_in[0];
  const float* y      = (const float*)d_in[1];
  const float* Wqkv_x = (const float*)d_in[3];
  const float* bqkv_x = (const float*)d_in[4];
  const float* Wqkv_y = (const float*)d_in[5];
  const float* bqkv_y = (const float*)d_in[6];
  const float* Wgs    = (const float*)d_in[7];
  const float* bgs    = (const float*)d_in[8];
  const float* Wgc    = (const float*)d_in[9];
  const float* bgc    = (const float*)d_in[10];
  const float* Wp     = (const float*)d_in[11];
  const float* bp     = (const float*)d_in[12];
  float* out = (float*)d_out;

  half_t* h = (half_t*)d_ws;
  half_t* x16    = h;  h += (size_t)B_ * T_ * C_;
  half_t* y16    = h;  h += (size_t)B_ * M_ * C_;
  half_t* WqkvxT = h;  h += (size_t)TC3 * C_;
  half_t* WqkvyT = h;  h += (size_t)TC3 * C_;
  half_t* WgsT   = h;  h += (size_t)C_ * C_;
  half_t* WgcT   = h;  h += (size_t)C_ * C_;
  half_t* WpT    = h;  h += (size_t)C_ * C_;
  half_t* qkvx   = h;  h += (size_t)B_ * T_ * 1024;
  half_t* qkvy   = h;  h += (size_t)B_ * M_ * 1024;
  half_t* vTx    = h;  h += (size_t)B_ * C_ * T_;
  half_t* vTy    = h;  h += (size_t)B_ * C_ * M_;
  half_t* sval   = h;  h += (size_t)B_ * T_ * C_;
  half_t* cval   = h;  h += (size_t)B_ * T_ * C_;
  half_t* z      = h;  h += (size_t)B_ * T_ * C_;
  float* biasb   = (float*)h;

  conv_all<<<3456, 256, 0, stream>>>(x, x16, y, y16,
                                     Wqkv_x, Wqkv_y, Wgs, Wgc, Wp,
                                     WqkvxT, WqkvyT, WgsT, WgcT, WpT);

  gemm_qkvt<<<864, 256, 0, stream>>>(x16, y16, WqkvxT, WqkvyT,
                                     bqkv_x, bqkv_y, qkvx, qkvy, vTx, vTy);

  bias_cross<<<1024, 256, 0, stream>>>(qkvx, qkvy, vTy, biasb, cval);

  self_attn_reg<<<512, 256, 0, stream>>>(qkvx, vTx, biasb, sval);

  gate_gemm64<<<dim3(4, 128), 256, 0, stream>>>(sval, cval, WgsT, WgcT, bgs, bgc, z);

  gemm_final64<<<dim3(4, 128), 256, 0, stream>>>(z, WpT, bp, out);
}